// Round 14
// baseline (247.605 us; speedup 1.0000x reference)
//
#include <hip/hip_runtime.h>

#define HD 128   // hidden / feature dim
#define PS 32    // pooling chunks per graph

typedef __bf16 bf16x8 __attribute__((ext_vector_type(8)));
typedef float  f32x16 __attribute__((ext_vector_type(16)));
typedef unsigned short u16x4 __attribute__((ext_vector_type(4)));
typedef _Float16 f16x4 __attribute__((ext_vector_type(4)));

__device__ inline unsigned short f2bf_rne(float f) {
  unsigned u = __builtin_bit_cast(unsigned, f);
  unsigned r = u + 0x7fffu + ((u >> 16) & 1u);
  return (unsigned short)(r >> 16);
}
__device__ inline float bf2f(unsigned short h) {
  unsigned u = ((unsigned)h) << 16;
  return __builtin_bit_cast(float, u);
}
__device__ inline void cvt4(float4 f, u16x4& h, u16x4& l) {
  h[0] = f2bf_rne(f.x); l[0] = f2bf_rne(f.x - bf2f(h[0]));
  h[1] = f2bf_rne(f.y); l[1] = f2bf_rne(f.y - bf2f(h[1]));
  h[2] = f2bf_rne(f.z); l[2] = f2bf_rne(f.z - bf2f(h[2]));
  h[3] = f2bf_rne(f.w); l[3] = f2bf_rne(f.w - bf2f(h[3]));
}

// ---------------- fused prep: xsplit | wsplit | init-cnt (independent outputs) ---------
__global__ __launch_bounds__(256) void k_prep(const float* __restrict__ x, unsigned short* __restrict__ ph,
                                              unsigned short* __restrict__ pl, int nelem4,
                                              const float* __restrict__ W1, const float* __restrict__ W2,
                                              const float* __restrict__ W3, unsigned short* __restrict__ wimg,
                                              int* __restrict__ cnt, int n, int nbX) {
  int b = blockIdx.x;
  int t = threadIdx.x;
  if (b < nbX) {                       // x -> split-bf16 planes
    int i = b * 256 + t;
    if (i < nelem4) {
      float4 f = ((const float4*)x)[i];
      u16x4 h, l;
      cvt4(f, h, l);
      ((u16x4*)ph)[i] = h;
      ((u16x4*)pl)[i] = l;
    }
  } else if (b < nbX + 51) {           // W split/transpose/pad LDS image
    int wb = b - nbX;
    const float* W = (wb < 17) ? W1 : (wb < 34) ? W2 : W3;
    unsigned short* out = wimg + (size_t)(wb / 17) * 34816;
    int base = ((wb % 17) * 256 + t) * 4;
#pragma unroll
    for (int p = 0; p < 4; ++p) {
      int flat = base + p;             // 0..17407
      int c = flat / 136, j = flat - c * 136;
      float v = (j < 128) ? W[(size_t)j * HD + c] : 0.f;
      unsigned short hi = f2bf_rne(v);
      float lo = (j < 128) ? (v - bf2f(hi)) : 0.f;
      out[(size_t)c * 136 + j] = hi;
      out[17408 + (size_t)c * 136 + j] = f2bf_rne(lo);
    }
  } else {                             // zero in-degree counters
    int i = (b - nbX - 51) * 256 + t;
    if (i < n) cnt[i] = 0;
  }
}

// ---------------- in-degree histogram over dst; record per-edge slot ----------------
__global__ __launch_bounds__(256) void k_hist(const int* __restrict__ dst, int* __restrict__ cnt,
                                              int* __restrict__ eslot, int e) {
  int i = blockIdx.x * 256 + threadIdx.x;
  if (i < e) eslot[i] = atomicAdd(&cnt[dst[i]], 1);
}

// ---------------- exclusive scan ----------------
__global__ __launch_bounds__(256) void k_scan1(const int* __restrict__ cnt, int* __restrict__ excl,
                                               int* __restrict__ bsum, int n) {
  __shared__ int s[256];
  int tid = threadIdx.x;
  int i = blockIdx.x * 256 + tid;
  int v = (i < n) ? cnt[i] : 0;
  s[tid] = v; __syncthreads();
  for (int off = 1; off < 256; off <<= 1) {
    int t = (tid >= off) ? s[tid - off] : 0;
    __syncthreads();
    s[tid] += t;
    __syncthreads();
  }
  if (i < n) excl[i] = s[tid] - v;
  if (tid == 255) bsum[blockIdx.x] = s[255];
}

__global__ __launch_bounds__(256) void k_scan2(int* __restrict__ bsum, int nb,
                                               int* __restrict__ gstart, int* __restrict__ gend, int g) {
  __shared__ int s[256];
  int tid = threadIdx.x;
  if (tid < g) { gstart[tid] = 0x7fffffff; gend[tid] = -1; }
  int v = (tid < nb) ? bsum[tid] : 0;
  s[tid] = v; __syncthreads();
  for (int off = 1; off < 256; off <<= 1) {
    int t = (tid >= off) ? s[tid - off] : 0;
    __syncthreads();
    s[tid] += t;
    __syncthreads();
  }
  if (tid < nb) bsum[tid] = s[tid] - v;
}

// rowptr += block offset; dis = rsqrt(1+deg); graph ranges via sorted-batch boundaries
__global__ __launch_bounds__(256) void k_finalize(int* __restrict__ rowptr, const int* __restrict__ bsum,
                                                  const int* __restrict__ cnt, float* __restrict__ dis,
                                                  const int* __restrict__ batch, int* __restrict__ gstart,
                                                  int* __restrict__ gend, int n) {
  int i = blockIdx.x * 256 + threadIdx.x;
  if (i >= n) return;
  rowptr[i] += bsum[blockIdx.x];
  dis[i] = rsqrtf(1.0f + (float)cnt[i]);
  int b = batch[i];
  if (i == 0 || batch[i - 1] != b) gstart[b] = i;
  if (i == n - 1 || batch[i + 1] != b) gend[b] = i;
}

// ---------------- CSR fill (atomic-free) ----------------
__global__ __launch_bounds__(256) void k_fill(const int* __restrict__ src, const int* __restrict__ dst,
                                              const int* __restrict__ rowptr, const int* __restrict__ eslot,
                                              int* __restrict__ csr, int e) {
  int i = blockIdx.x * 256 + threadIdx.x;
  if (i >= e) return;
  csr[rowptr[dst[i]] + eslot[i]] = src[i];
}

// ---------------- split-bf16 MFMA GEMM, single K=128 tile, one barrier, 16 waves ----------
// A pre-split (hi/lo ushort planes); C written as fp16 (gather reads 256B rows).
__global__ __launch_bounds__(1024) void k_gemm(const unsigned short* __restrict__ AH,
                                               const unsigned short* __restrict__ AL,
                                               const unsigned short* __restrict__ wimg_l,
                                               const float* __restrict__ rowscale,
                                               _Float16* __restrict__ C, int M) {
  __shared__ unsigned short alds[2][128][136];   // 69632 B
  __shared__ unsigned short wlds[2][128][136];   // 69632 B
  int t = threadIdx.x;
  int row0 = blockIdx.x * 128;
  char* ab = (char*)alds;
  char* wb = (char*)wlds;
  const int PL = 128 * 272;

  // stage A: 2 planes x 2048 float4 slots (coalesced), dest padded rows
  {
    const float4* sH = (const float4*)(AH + (size_t)row0 * HD);
    const float4* sL = (const float4*)(AL + (size_t)row0 * HD);
#pragma unroll
    for (int u = 0; u < 2; ++u) {
      int s = u * 1024 + t;              // 0..2047
      int r = s >> 4, c = s & 15;
      *(float4*)(ab + r * 272 + c * 16) = sH[s];
      *(float4*)(ab + PL + r * 272 + c * 16) = sL[s];
    }
  }
  // stage W: linear copy of pre-formatted image (4352 float4)
  {
    const float4* sW = (const float4*)wimg_l;
    float4* dW = (float4*)wb;
#pragma unroll
    for (int u = 0; u < 4; ++u) dW[u * 1024 + t] = sW[u * 1024 + t];
    if (t < 256) dW[4096 + t] = sW[4096 + t];
  }
  __syncthreads();

  int w = t >> 6, lane = t & 63;
  int l31 = lane & 31, lhi = lane >> 5;
  int wr = (w >> 2) * 32, wc = (w & 3) * 32;

  f32x16 acc;
#pragma unroll
  for (int i = 0; i < 16; ++i) acc[i] = 0.f;

#pragma unroll
  for (int ks = 0; ks < 8; ++ks) {
    int ko = ks * 32 + lhi * 16;
    bf16x8 ah = *(const bf16x8*)(ab + (wr + l31) * 272 + ko);
    bf16x8 al = *(const bf16x8*)(ab + PL + (wr + l31) * 272 + ko);
    bf16x8 bh = *(const bf16x8*)(wb + (wc + l31) * 272 + ko);
    bf16x8 bl = *(const bf16x8*)(wb + PL + (wc + l31) * 272 + ko);
    acc = __builtin_amdgcn_mfma_f32_32x32x16_bf16(ah, bh, acc, 0, 0, 0);
    acc = __builtin_amdgcn_mfma_f32_32x32x16_bf16(ah, bl, acc, 0, 0, 0);
    acc = __builtin_amdgcn_mfma_f32_32x32x16_bf16(al, bh, acc, 0, 0, 0);
  }

  // epilogue: C/D layout col = lane&31, row = (r&3) + 8*(r>>2) + 4*lhi; fp16 store
  int col = wc + l31;
  int rbase = row0 + wr + 4 * lhi;
#pragma unroll
  for (int r = 0; r < 16; ++r) {
    int row = rbase + (r & 3) + 8 * (r >> 2);
    if (row < M) C[(size_t)row * HD + col] = (_Float16)(rowscale[row] * acc[r]);
  }
}

// ---------------- gather aggregation + self loop + bias + relu ----------------
// fp16 C rows (256B) pre-scaled by dis: one HALF-WAVE per node, 8 independent
// row streams per half-wave (16/wave). No cross-lane combine needed.
__global__ __launch_bounds__(256) void k_gather(const _Float16* __restrict__ C, const float* __restrict__ dis,
                                                const int* __restrict__ rowptr, const int* __restrict__ cnt,
                                                const int* __restrict__ csr, const float* __restrict__ bias,
                                                float* __restrict__ outF, unsigned short* __restrict__ outH,
                                                unsigned short* __restrict__ outL, int n) {
  int lane = threadIdx.x & 63;
  int wid = threadIdx.x >> 6;
  int half = lane >> 5;
  int l32 = lane & 31;
  int node = blockIdx.x * 8 + wid * 2 + half;
  if (node >= n) return;
  int coff = l32 * 4;
  int s = rowptr[node];
  int deg = cnt[node];

  float dn = dis[node];
  f16x4 sh = *(const f16x4*)(C + (size_t)node * HD + coff);
  float4 bb = *(const float4*)(bias + coff);

  float4 a0 = make_float4(0.f, 0.f, 0.f, 0.f);
  float4 a1 = a0, a2 = a0, a3 = a0, a4 = a0, a5 = a0, a6 = a0, a7 = a0;
  int i = 0;
  for (; i + 8 <= deg; i += 8) {          // 8 independent row streams per half-wave
    int i0 = csr[s + i];
    int i1 = csr[s + i + 1];
    int i2 = csr[s + i + 2];
    int i3 = csr[s + i + 3];
    int i4 = csr[s + i + 4];
    int i5 = csr[s + i + 5];
    int i6 = csr[s + i + 6];
    int i7 = csr[s + i + 7];
    f16x4 v0 = *(const f16x4*)(C + (size_t)i0 * HD + coff);
    f16x4 v1 = *(const f16x4*)(C + (size_t)i1 * HD + coff);
    f16x4 v2 = *(const f16x4*)(C + (size_t)i2 * HD + coff);
    f16x4 v3 = *(const f16x4*)(C + (size_t)i3 * HD + coff);
    f16x4 v4 = *(const f16x4*)(C + (size_t)i4 * HD + coff);
    f16x4 v5 = *(const f16x4*)(C + (size_t)i5 * HD + coff);
    f16x4 v6 = *(const f16x4*)(C + (size_t)i6 * HD + coff);
    f16x4 v7 = *(const f16x4*)(C + (size_t)i7 * HD + coff);
    a0.x += (float)v0[0]; a0.y += (float)v0[1]; a0.z += (float)v0[2]; a0.w += (float)v0[3];
    a1.x += (float)v1[0]; a1.y += (float)v1[1]; a1.z += (float)v1[2]; a1.w += (float)v1[3];
    a2.x += (float)v2[0]; a2.y += (float)v2[1]; a2.z += (float)v2[2]; a2.w += (float)v2[3];
    a3.x += (float)v3[0]; a3.y += (float)v3[1]; a3.z += (float)v3[2]; a3.w += (float)v3[3];
    a4.x += (float)v4[0]; a4.y += (float)v4[1]; a4.z += (float)v4[2]; a4.w += (float)v4[3];
    a5.x += (float)v5[0]; a5.y += (float)v5[1]; a5.z += (float)v5[2]; a5.w += (float)v5[3];
    a6.x += (float)v6[0]; a6.y += (float)v6[1]; a6.z += (float)v6[2]; a6.w += (float)v6[3];
    a7.x += (float)v7[0]; a7.y += (float)v7[1]; a7.z += (float)v7[2]; a7.w += (float)v7[3];
  }
  if (i + 4 <= deg) {                     // 4-stream step
    int i0 = csr[s + i];
    int i1 = csr[s + i + 1];
    int i2 = csr[s + i + 2];
    int i3 = csr[s + i + 3];
    f16x4 v0 = *(const f16x4*)(C + (size_t)i0 * HD + coff);
    f16x4 v1 = *(const f16x4*)(C + (size_t)i1 * HD + coff);
    f16x4 v2 = *(const f16x4*)(C + (size_t)i2 * HD + coff);
    f16x4 v3 = *(const f16x4*)(C + (size_t)i3 * HD + coff);
    a0.x += (float)v0[0]; a0.y += (float)v0[1]; a0.z += (float)v0[2]; a0.w += (float)v0[3];
    a1.x += (float)v1[0]; a1.y += (float)v1[1]; a1.z += (float)v1[2]; a1.w += (float)v1[3];
    a2.x += (float)v2[0]; a2.y += (float)v2[1]; a2.z += (float)v2[2]; a2.w += (float)v2[3];
    a3.x += (float)v3[0]; a3.y += (float)v3[1]; a3.z += (float)v3[2]; a3.w += (float)v3[3];
    i += 4;
  }
  for (; i < deg; ++i) {                  // tail (up to 3)
    int i0 = csr[s + i];
    f16x4 v0 = *(const f16x4*)(C + (size_t)i0 * HD + coff);
    a0.x += (float)v0[0]; a0.y += (float)v0[1]; a0.z += (float)v0[2]; a0.w += (float)v0[3];
  }
  a0.x += a1.x + a2.x + a3.x + a4.x + a5.x + a6.x + a7.x;
  a0.y += a1.y + a2.y + a3.y + a4.y + a5.y + a6.y + a7.y;
  a0.z += a1.z + a2.z + a3.z + a4.z + a5.z + a6.z + a7.z;
  a0.w += a1.w + a2.w + a3.w + a4.w + a5.w + a6.w + a7.w;

  float4 r;
  r.x = fmaxf(dn * (a0.x + (float)sh[0]) + bb.x, 0.f);
  r.y = fmaxf(dn * (a0.y + (float)sh[1]) + bb.y, 0.f);
  r.z = fmaxf(dn * (a0.z + (float)sh[2]) + bb.z, 0.f);
  r.w = fmaxf(dn * (a0.w + (float)sh[3]) + bb.w, 0.f);
  if (outF) {
    *(float4*)(outF + (size_t)node * HD + coff) = r;
  } else {
    u16x4 h, l;
    cvt4(r, h, l);
    *(u16x4*)(outH + (size_t)node * HD + coff) = h;
    *(u16x4*)(outL + (size_t)node * HD + coff) = l;
  }
}

// ---------------- pooling stage 1 ----------------
__global__ __launch_bounds__(128) void k_pool1(const float* __restrict__ h, const int* __restrict__ gstart,
                                               const int* __restrict__ gend, float* __restrict__ psum,
                                               float* __restrict__ pmax) {
  int g = blockIdx.x, sidx = blockIdx.y, c = threadIdx.x;
  int s = gstart[g], e = gend[g];
  float sum = 0.f, mx = 0.f;
  if (s <= e) {
    int len = e - s + 1;
    int c0 = s + (int)(((long long)len * sidx) / PS);
    int c1 = s + (int)(((long long)len * (sidx + 1)) / PS);
    for (int i = c0; i < c1; ++i) {
      float v = h[(size_t)i * HD + c];
      sum += v;
      mx = fmaxf(mx, v);
    }
  }
  size_t o = ((size_t)g * PS + sidx) * HD + c;
  psum[o] = sum;
  pmax[o] = mx;
}

// ---------------- pooling stage 2 fused with MLP ----------------
__global__ __launch_bounds__(128) void k_pool2mlp(const float* __restrict__ psum, const float* __restrict__ pmax,
                                                  const int* __restrict__ gstart, const int* __restrict__ gend,
                                                  const float* __restrict__ Wf1, const float* __restrict__ bf1,
                                                  const float* __restrict__ Wf2, const float* __restrict__ bf2,
                                                  float* __restrict__ out) {
  __shared__ float p[256];
  __shared__ float red[128];
  int g = blockIdx.x, t = threadIdx.x;
  float sum = 0.f, mx = 0.f;
  for (int sidx = 0; sidx < PS; ++sidx) {
    size_t o = ((size_t)g * PS + sidx) * HD + t;
    sum += psum[o];
    mx = fmaxf(mx, pmax[o]);
  }
  int s = gstart[g], e = gend[g];
  float cntf = (s <= e) ? (float)(e - s + 1) : 1.0f;
  p[t] = sum / cntf;
  p[t + 128] = mx;
  __syncthreads();
  float acc = bf1[t];
  for (int k = 0; k < 256; ++k) acc += p[k] * Wf1[k * HD + t];
  float hv = fmaxf(acc, 0.f);
  red[t] = hv * Wf2[t];
  __syncthreads();
  for (int off = 64; off > 0; off >>= 1) {
    if (t < off) red[t] += red[t + off];
    __syncthreads();
  }
  if (t == 0) out[g] = red[0] + bf2[0];
}

extern "C" void kernel_launch(void* const* d_in, const int* in_sizes, int n_in,
                              void* d_out, int out_size, void* d_ws, size_t ws_size,
                              hipStream_t stream) {
  const float* x   = (const float*)d_in[0];
  const int*   ei  = (const int*)d_in[1];
  const int*   bat = (const int*)d_in[2];
  const float* W1  = (const float*)d_in[3];
  const float* b1  = (const float*)d_in[4];
  const float* W2  = (const float*)d_in[5];
  const float* b2  = (const float*)d_in[6];
  const float* W3  = (const float*)d_in[7];
  const float* b3  = (const float*)d_in[8];
  const float* Wf1 = (const float*)d_in[9];
  const float* bf1 = (const float*)d_in[10];
  const float* Wf2 = (const float*)d_in[11];
  const float* bf2 = (const float*)d_in[12];

  int N = in_sizes[0] / HD;
  int E = in_sizes[1] / 2;
  int G = out_size;

  int gb = (N + 127) / 128;      // gemm blocks
  int Rpad = gb * 128;           // padded row count

  char* w = (char*)d_ws;
  size_t off = 0;
  auto alloc = [&](size_t bytes) -> void* {
    void* p = w + off;
    off = (off + bytes + 255) & ~(size_t)255;
    return p;
  };
  unsigned short* pH0 = (unsigned short*)alloc((size_t)Rpad * HD * 2);
  unsigned short* pL0 = (unsigned short*)alloc((size_t)Rpad * HD * 2);
  unsigned short* pH1 = (unsigned short*)alloc((size_t)Rpad * HD * 2);
  unsigned short* pL1 = (unsigned short*)alloc((size_t)Rpad * HD * 2);
  _Float16* Cbuf = (_Float16*)alloc((size_t)Rpad * HD * 2);
  float* Hf     = (float*)alloc((size_t)N * HD * 4);
  int*   csr    = (int*)alloc((size_t)E * 4);
  int*   cnt    = (int*)alloc((size_t)N * 4);
  int*   rowptr = (int*)alloc((size_t)N * 4);
  float* dis    = (float*)alloc((size_t)N * 4);
  int*   bsum   = (int*)alloc(256 * 4);
  int*   gstart = (int*)alloc((size_t)G * 4);
  int*   gend   = (int*)alloc((size_t)G * 4);
  float* psum   = (float*)alloc((size_t)G * PS * HD * 4);
  float* pmax   = (float*)alloc((size_t)G * PS * HD * 4);
  unsigned short* wimg = (unsigned short*)alloc((size_t)3 * 34816 * 2);
  int*   eslot  = (int*)Hf;      // alias: eslot dead before last gather writes Hf

  int nbN = (N + 255) / 256;
  int nbE = (E + 255) / 256;
  int nelem4 = N * HD / 4;
  int nbX = (nelem4 + 255) / 256;

  k_prep<<<nbX + 51 + nbN, 256, 0, stream>>>(x, pH0, pL0, nelem4, W1, W2, W3, wimg, cnt, N, nbX);
  k_hist<<<nbE, 256, 0, stream>>>(ei + E, cnt, eslot, E);
  k_scan1<<<nbN, 256, 0, stream>>>(cnt, rowptr, bsum, N);
  k_scan2<<<1, 256, 0, stream>>>(bsum, nbN, gstart, gend, G);
  k_finalize<<<nbN, 256, 0, stream>>>(rowptr, bsum, cnt, dis, bat, gstart, gend, N);
  k_fill<<<nbE, 256, 0, stream>>>(ei, ei + E, rowptr, eslot, csr, E);

  int ab = (N + 7) / 8;
  k_gemm<<<gb, 1024, 0, stream>>>(pH0, pL0, wimg, dis, Cbuf, N);
  k_gather<<<ab, 256, 0, stream>>>(Cbuf, dis, rowptr, cnt, csr, b1, nullptr, pH1, pL1, N);
  k_gemm<<<gb, 1024, 0, stream>>>(pH1, pL1, wimg + 34816, dis, Cbuf, N);
  k_gather<<<ab, 256, 0, stream>>>(Cbuf, dis, rowptr, cnt, csr, b2, nullptr, pH0, pL0, N);
  k_gemm<<<gb, 1024, 0, stream>>>(pH0, pL0, wimg + 69632, dis, Cbuf, N);
  k_gather<<<ab, 256, 0, stream>>>(Cbuf, dis, rowptr, cnt, csr, b3, Hf, nullptr, nullptr, N);

  dim3 pgrid(G, PS);
  k_pool1<<<pgrid, 128, 0, stream>>>(Hf, gstart, gend, psum, pmax);
  k_pool2mlp<<<G, 128, 0, stream>>>(psum, pmax, gstart, gend, Wf1, bf1, Wf2, bf2, (float*)d_out);
}

// Round 15
// 236.411 us; speedup vs baseline: 1.0474x; 1.0474x over previous
//
#include <hip/hip_runtime.h>

#define HD 128   // hidden / feature dim
#define PS 32    // pooling chunks per graph

typedef __bf16 bf16x8 __attribute__((ext_vector_type(8)));
typedef float  f32x16 __attribute__((ext_vector_type(16)));
typedef unsigned short u16x4 __attribute__((ext_vector_type(4)));
typedef _Float16 f16x4 __attribute__((ext_vector_type(4)));

__device__ inline unsigned short f2bf_rne(float f) {
  unsigned u = __builtin_bit_cast(unsigned, f);
  unsigned r = u + 0x7fffu + ((u >> 16) & 1u);
  return (unsigned short)(r >> 16);
}
__device__ inline float bf2f(unsigned short h) {
  unsigned u = ((unsigned)h) << 16;
  return __builtin_bit_cast(float, u);
}
__device__ inline void cvt4(float4 f, u16x4& h, u16x4& l) {
  h[0] = f2bf_rne(f.x); l[0] = f2bf_rne(f.x - bf2f(h[0]));
  h[1] = f2bf_rne(f.y); l[1] = f2bf_rne(f.y - bf2f(h[1]));
  h[2] = f2bf_rne(f.z); l[2] = f2bf_rne(f.z - bf2f(h[2]));
  h[3] = f2bf_rne(f.w); l[3] = f2bf_rne(f.w - bf2f(h[3]));
}

// ---------------- fused prep: xsplit | wsplit | init-cnt + graph sentinels ----------------
__global__ __launch_bounds__(256) void k_prep(const float* __restrict__ x, unsigned short* __restrict__ ph,
                                              unsigned short* __restrict__ pl, int nelem4,
                                              const float* __restrict__ W1, const float* __restrict__ W2,
                                              const float* __restrict__ W3, unsigned short* __restrict__ wimg,
                                              int* __restrict__ cnt, int n, int nbX,
                                              int* __restrict__ gstart, int* __restrict__ gend, int g) {
  int b = blockIdx.x;
  int t = threadIdx.x;
  if (b < nbX) {                       // x -> split-bf16 planes
    int i = b * 256 + t;
    if (i < nelem4) {
      float4 f = ((const float4*)x)[i];
      u16x4 h, l;
      cvt4(f, h, l);
      ((u16x4*)ph)[i] = h;
      ((u16x4*)pl)[i] = l;
    }
  } else if (b < nbX + 51) {           // W split/transpose/pad LDS image
    int wb = b - nbX;
    const float* W = (wb < 17) ? W1 : (wb < 34) ? W2 : W3;
    unsigned short* out = wimg + (size_t)(wb / 17) * 34816;
    int base = ((wb % 17) * 256 + t) * 4;
#pragma unroll
    for (int p = 0; p < 4; ++p) {
      int flat = base + p;             // 0..17407
      int c = flat / 136, j = flat - c * 136;
      float v = (j < 128) ? W[(size_t)j * HD + c] : 0.f;
      unsigned short hi = f2bf_rne(v);
      float lo = (j < 128) ? (v - bf2f(hi)) : 0.f;
      out[(size_t)c * 136 + j] = hi;
      out[17408 + (size_t)c * 136 + j] = f2bf_rne(lo);
    }
  } else {                             // zero in-degree counters (+ sentinels, first block)
    int bb = b - nbX - 51;
    int i = bb * 256 + t;
    if (i < n) cnt[i] = 0;
    if (bb == 0 && t < g) { gstart[t] = 0x7fffffff; gend[t] = -1; }
  }
}

// ---------------- in-degree histogram over dst; record per-edge slot ----------------
__global__ __launch_bounds__(256) void k_hist(const int* __restrict__ dst, int* __restrict__ cnt,
                                              int* __restrict__ eslot, int e) {
  int i = blockIdx.x * 256 + threadIdx.x;
  if (i < e) eslot[i] = atomicAdd(&cnt[dst[i]], 1);
}

// ---------------- per-block exclusive scan; bsum[b] = block b's total ----------------
__global__ __launch_bounds__(256) void k_scan1(const int* __restrict__ cnt, int* __restrict__ excl,
                                               int* __restrict__ bsum, int n) {
  __shared__ int s[256];
  int tid = threadIdx.x;
  int i = blockIdx.x * 256 + tid;
  int v = (i < n) ? cnt[i] : 0;
  s[tid] = v; __syncthreads();
  for (int off = 1; off < 256; off <<= 1) {
    int t = (tid >= off) ? s[tid - off] : 0;
    __syncthreads();
    s[tid] += t;
    __syncthreads();
  }
  if (i < n) excl[i] = s[tid] - v;
  if (tid == 255) bsum[blockIdx.x] = s[255];
}

// rowptr += prefix(bsum[0..b)); dis = rsqrt(1+deg); graph ranges via sorted-batch
// boundaries. Each block computes its own bsum prefix (<=256 ints, wave 0).
__global__ __launch_bounds__(256) void k_finalize(int* __restrict__ rowptr, const int* __restrict__ bsum,
                                                  const int* __restrict__ cnt, float* __restrict__ dis,
                                                  const int* __restrict__ batch, int* __restrict__ gstart,
                                                  int* __restrict__ gend, int n) {
  __shared__ int spre;
  int tid = threadIdx.x;
  int nb = blockIdx.x;                 // need sum of bsum[0..nb)
  if (tid < 64) {
    int acc = 0;
    for (int j = tid; j < nb; j += 64) acc += bsum[j];
#pragma unroll
    for (int m = 1; m < 64; m <<= 1) acc += __shfl_xor(acc, m);
    if (tid == 0) spre = acc;
  }
  __syncthreads();
  int pre = spre;
  int i = nb * 256 + tid;
  if (i >= n) return;
  rowptr[i] += pre;
  dis[i] = rsqrtf(1.0f + (float)cnt[i]);
  int b = batch[i];
  if (i == 0 || batch[i - 1] != b) gstart[b] = i;
  if (i == n - 1 || batch[i + 1] != b) gend[b] = i;
}

// ---------------- CSR fill (atomic-free) ----------------
__global__ __launch_bounds__(256) void k_fill(const int* __restrict__ src, const int* __restrict__ dst,
                                              const int* __restrict__ rowptr, const int* __restrict__ eslot,
                                              int* __restrict__ csr, int e) {
  int i = blockIdx.x * 256 + threadIdx.x;
  if (i >= e) return;
  csr[rowptr[dst[i]] + eslot[i]] = src[i];
}

// ---------------- split-bf16 MFMA GEMM, single K=128 tile, one barrier, 16 waves ----------
// A pre-split (hi/lo ushort planes); C written as fp16 (gather reads 256B rows).
__global__ __launch_bounds__(1024) void k_gemm(const unsigned short* __restrict__ AH,
                                               const unsigned short* __restrict__ AL,
                                               const unsigned short* __restrict__ wimg_l,
                                               const float* __restrict__ rowscale,
                                               _Float16* __restrict__ C, int M) {
  __shared__ unsigned short alds[2][128][136];   // 69632 B
  __shared__ unsigned short wlds[2][128][136];   // 69632 B
  int t = threadIdx.x;
  int row0 = blockIdx.x * 128;
  char* ab = (char*)alds;
  char* wb = (char*)wlds;
  const int PL = 128 * 272;

  // stage A: 2 planes x 2048 float4 slots (coalesced), dest padded rows
  {
    const float4* sH = (const float4*)(AH + (size_t)row0 * HD);
    const float4* sL = (const float4*)(AL + (size_t)row0 * HD);
#pragma unroll
    for (int u = 0; u < 2; ++u) {
      int s = u * 1024 + t;              // 0..2047
      int r = s >> 4, c = s & 15;
      *(float4*)(ab + r * 272 + c * 16) = sH[s];
      *(float4*)(ab + PL + r * 272 + c * 16) = sL[s];
    }
  }
  // stage W: linear copy of pre-formatted image (4352 float4)
  {
    const float4* sW = (const float4*)wimg_l;
    float4* dW = (float4*)wb;
#pragma unroll
    for (int u = 0; u < 4; ++u) dW[u * 1024 + t] = sW[u * 1024 + t];
    if (t < 256) dW[4096 + t] = sW[4096 + t];
  }
  __syncthreads();

  int w = t >> 6, lane = t & 63;
  int l31 = lane & 31, lhi = lane >> 5;
  int wr = (w >> 2) * 32, wc = (w & 3) * 32;

  f32x16 acc;
#pragma unroll
  for (int i = 0; i < 16; ++i) acc[i] = 0.f;

#pragma unroll
  for (int ks = 0; ks < 8; ++ks) {
    int ko = ks * 32 + lhi * 16;
    bf16x8 ah = *(const bf16x8*)(ab + (wr + l31) * 272 + ko);
    bf16x8 al = *(const bf16x8*)(ab + PL + (wr + l31) * 272 + ko);
    bf16x8 bh = *(const bf16x8*)(wb + (wc + l31) * 272 + ko);
    bf16x8 bl = *(const bf16x8*)(wb + PL + (wc + l31) * 272 + ko);
    acc = __builtin_amdgcn_mfma_f32_32x32x16_bf16(ah, bh, acc, 0, 0, 0);
    acc = __builtin_amdgcn_mfma_f32_32x32x16_bf16(ah, bl, acc, 0, 0, 0);
    acc = __builtin_amdgcn_mfma_f32_32x32x16_bf16(al, bh, acc, 0, 0, 0);
  }

  // epilogue: C/D layout col = lane&31, row = (r&3) + 8*(r>>2) + 4*lhi; fp16 store
  int col = wc + l31;
  int rbase = row0 + wr + 4 * lhi;
#pragma unroll
  for (int r = 0; r < 16; ++r) {
    int row = rbase + (r & 3) + 8 * (r >> 2);
    if (row < M) C[(size_t)row * HD + col] = (_Float16)(rowscale[row] * acc[r]);
  }
}

// ---------------- gather aggregation + self loop + bias + relu ----------------
// fp16 C rows (256B) pre-scaled by dis: one HALF-WAVE per node (32 lanes x 8B = row).
// Each half-wave walks its own edge list, 4 independent row streams in flight ->
// 8 streams/wave. No cross-lane combine needed. (r13 form — measured optimum.)
__global__ __launch_bounds__(256) void k_gather(const _Float16* __restrict__ C, const float* __restrict__ dis,
                                                const int* __restrict__ rowptr, const int* __restrict__ cnt,
                                                const int* __restrict__ csr, const float* __restrict__ bias,
                                                float* __restrict__ outF, unsigned short* __restrict__ outH,
                                                unsigned short* __restrict__ outL, int n) {
  int lane = threadIdx.x & 63;
  int wid = threadIdx.x >> 6;
  int half = lane >> 5;
  int l32 = lane & 31;
  int node = blockIdx.x * 8 + wid * 2 + half;
  if (node >= n) return;
  int coff = l32 * 4;
  int s = rowptr[node];
  int deg = cnt[node];

  float dn = dis[node];
  f16x4 sh = *(const f16x4*)(C + (size_t)node * HD + coff);
  float4 bb = *(const float4*)(bias + coff);

  float4 a0 = make_float4(0.f, 0.f, 0.f, 0.f);
  float4 a1 = a0, a2 = a0, a3 = a0;
  int i = 0;
  for (; i + 4 <= deg; i += 4) {          // 4 independent row streams per half-wave
    int i0 = csr[s + i];
    int i1 = csr[s + i + 1];
    int i2 = csr[s + i + 2];
    int i3 = csr[s + i + 3];
    f16x4 v0 = *(const f16x4*)(C + (size_t)i0 * HD + coff);
    f16x4 v1 = *(const f16x4*)(C + (size_t)i1 * HD + coff);
    f16x4 v2 = *(const f16x4*)(C + (size_t)i2 * HD + coff);
    f16x4 v3 = *(const f16x4*)(C + (size_t)i3 * HD + coff);
    a0.x += (float)v0[0]; a0.y += (float)v0[1]; a0.z += (float)v0[2]; a0.w += (float)v0[3];
    a1.x += (float)v1[0]; a1.y += (float)v1[1]; a1.z += (float)v1[2]; a1.w += (float)v1[3];
    a2.x += (float)v2[0]; a2.y += (float)v2[1]; a2.z += (float)v2[2]; a2.w += (float)v2[3];
    a3.x += (float)v3[0]; a3.y += (float)v3[1]; a3.z += (float)v3[2]; a3.w += (float)v3[3];
  }
  for (; i < deg; ++i) {                  // tail (up to 3)
    int i0 = csr[s + i];
    f16x4 v0 = *(const f16x4*)(C + (size_t)i0 * HD + coff);
    a0.x += (float)v0[0]; a0.y += (float)v0[1]; a0.z += (float)v0[2]; a0.w += (float)v0[3];
  }
  a0.x += a1.x + a2.x + a3.x;
  a0.y += a1.y + a2.y + a3.y;
  a0.z += a1.z + a2.z + a3.z;
  a0.w += a1.w + a2.w + a3.w;

  float4 r;
  r.x = fmaxf(dn * (a0.x + (float)sh[0]) + bb.x, 0.f);
  r.y = fmaxf(dn * (a0.y + (float)sh[1]) + bb.y, 0.f);
  r.z = fmaxf(dn * (a0.z + (float)sh[2]) + bb.z, 0.f);
  r.w = fmaxf(dn * (a0.w + (float)sh[3]) + bb.w, 0.f);
  if (outF) {
    *(float4*)(outF + (size_t)node * HD + coff) = r;
  } else {
    u16x4 h, l;
    cvt4(r, h, l);
    *(u16x4*)(outH + (size_t)node * HD + coff) = h;
    *(u16x4*)(outL + (size_t)node * HD + coff) = l;
  }
}

// ---------------- pooling stage 1 ----------------
__global__ __launch_bounds__(128) void k_pool1(const float* __restrict__ h, const int* __restrict__ gstart,
                                               const int* __restrict__ gend, float* __restrict__ psum,
                                               float* __restrict__ pmax) {
  int g = blockIdx.x, sidx = blockIdx.y, c = threadIdx.x;
  int s = gstart[g], e = gend[g];
  float sum = 0.f, mx = 0.f;
  if (s <= e) {
    int len = e - s + 1;
    int c0 = s + (int)(((long long)len * sidx) / PS);
    int c1 = s + (int)(((long long)len * (sidx + 1)) / PS);
    for (int i = c0; i < c1; ++i) {
      float v = h[(size_t)i * HD + c];
      sum += v;
      mx = fmaxf(mx, v);
    }
  }
  size_t o = ((size_t)g * PS + sidx) * HD + c;
  psum[o] = sum;
  pmax[o] = mx;
}

// ---------------- pooling stage 2 fused with MLP ----------------
__global__ __launch_bounds__(128) void k_pool2mlp(const float* __restrict__ psum, const float* __restrict__ pmax,
                                                  const int* __restrict__ gstart, const int* __restrict__ gend,
                                                  const float* __restrict__ Wf1, const float* __restrict__ bf1,
                                                  const float* __restrict__ Wf2, const float* __restrict__ bf2,
                                                  float* __restrict__ out) {
  __shared__ float p[256];
  __shared__ float red[128];
  int g = blockIdx.x, t = threadIdx.x;
  float sum = 0.f, mx = 0.f;
  for (int sidx = 0; sidx < PS; ++sidx) {
    size_t o = ((size_t)g * PS + sidx) * HD + t;
    sum += psum[o];
    mx = fmaxf(mx, pmax[o]);
  }
  int s = gstart[g], e = gend[g];
  float cntf = (s <= e) ? (float)(e - s + 1) : 1.0f;
  p[t] = sum / cntf;
  p[t + 128] = mx;
  __syncthreads();
  float acc = bf1[t];
  for (int k = 0; k < 256; ++k) acc += p[k] * Wf1[k * HD + t];
  float hv = fmaxf(acc, 0.f);
  red[t] = hv * Wf2[t];
  __syncthreads();
  for (int off = 64; off > 0; off >>= 1) {
    if (t < off) red[t] += red[t + off];
    __syncthreads();
  }
  if (t == 0) out[g] = red[0] + bf2[0];
}

extern "C" void kernel_launch(void* const* d_in, const int* in_sizes, int n_in,
                              void* d_out, int out_size, void* d_ws, size_t ws_size,
                              hipStream_t stream) {
  const float* x   = (const float*)d_in[0];
  const int*   ei  = (const int*)d_in[1];
  const int*   bat = (const int*)d_in[2];
  const float* W1  = (const float*)d_in[3];
  const float* b1  = (const float*)d_in[4];
  const float* W2  = (const float*)d_in[5];
  const float* b2  = (const float*)d_in[6];
  const float* W3  = (const float*)d_in[7];
  const float* b3  = (const float*)d_in[8];
  const float* Wf1 = (const float*)d_in[9];
  const float* bf1 = (const float*)d_in[10];
  const float* Wf2 = (const float*)d_in[11];
  const float* bf2 = (const float*)d_in[12];

  int N = in_sizes[0] / HD;
  int E = in_sizes[1] / 2;
  int G = out_size;

  int gb = (N + 127) / 128;      // gemm blocks
  int Rpad = gb * 128;           // padded row count

  char* w = (char*)d_ws;
  size_t off = 0;
  auto alloc = [&](size_t bytes) -> void* {
    void* p = w + off;
    off = (off + bytes + 255) & ~(size_t)255;
    return p;
  };
  unsigned short* pH0 = (unsigned short*)alloc((size_t)Rpad * HD * 2);
  unsigned short* pL0 = (unsigned short*)alloc((size_t)Rpad * HD * 2);
  unsigned short* pH1 = (unsigned short*)alloc((size_t)Rpad * HD * 2);
  unsigned short* pL1 = (unsigned short*)alloc((size_t)Rpad * HD * 2);
  _Float16* Cbuf = (_Float16*)alloc((size_t)Rpad * HD * 2);
  float* Hf     = (float*)alloc((size_t)N * HD * 4);
  int*   csr    = (int*)alloc((size_t)E * 4);
  int*   cnt    = (int*)alloc((size_t)N * 4);
  int*   rowptr = (int*)alloc((size_t)N * 4);
  float* dis    = (float*)alloc((size_t)N * 4);
  int*   bsum   = (int*)alloc(256 * 4);
  int*   gstart = (int*)alloc((size_t)G * 4);
  int*   gend   = (int*)alloc((size_t)G * 4);
  float* psum   = (float*)alloc((size_t)G * PS * HD * 4);
  float* pmax   = (float*)alloc((size_t)G * PS * HD * 4);
  unsigned short* wimg = (unsigned short*)alloc((size_t)3 * 34816 * 2);
  int*   eslot  = (int*)Hf;      // alias: eslot dead before last gather writes Hf

  int nbN = (N + 255) / 256;
  int nbE = (E + 255) / 256;
  int nelem4 = N * HD / 4;
  int nbX = (nelem4 + 255) / 256;

  k_prep<<<nbX + 51 + nbN, 256, 0, stream>>>(x, pH0, pL0, nelem4, W1, W2, W3, wimg, cnt, N, nbX,
                                             gstart, gend, G);
  k_hist<<<nbE, 256, 0, stream>>>(ei + E, cnt, eslot, E);
  k_scan1<<<nbN, 256, 0, stream>>>(cnt, rowptr, bsum, N);
  k_finalize<<<nbN, 256, 0, stream>>>(rowptr, bsum, cnt, dis, bat, gstart, gend, N);
  k_fill<<<nbE, 256, 0, stream>>>(ei, ei + E, rowptr, eslot, csr, E);

  int ab = (N + 7) / 8;
  k_gemm<<<gb, 1024, 0, stream>>>(pH0, pL0, wimg, dis, Cbuf, N);
  k_gather<<<ab, 256, 0, stream>>>(Cbuf, dis, rowptr, cnt, csr, b1, nullptr, pH1, pL1, N);
  k_gemm<<<gb, 1024, 0, stream>>>(pH1, pL1, wimg + 34816, dis, Cbuf, N);
  k_gather<<<ab, 256, 0, stream>>>(Cbuf, dis, rowptr, cnt, csr, b2, nullptr, pH0, pL0, N);
  k_gemm<<<gb, 1024, 0, stream>>>(pH0, pL0, wimg + 69632, dis, Cbuf, N);
  k_gather<<<ab, 256, 0, stream>>>(Cbuf, dis, rowptr, cnt, csr, b3, Hf, nullptr, nullptr, N);

  dim3 pgrid(G, PS);
  k_pool1<<<pgrid, 128, 0, stream>>>(Hf, gstart, gend, psum, pmax);
  k_pool2mlp<<<G, 128, 0, stream>>>(psum, pmax, gstart, gend, Wf1, bf1, Wf2, bf2, (float*)d_out);
}

// Round 17
// 218.390 us; speedup vs baseline: 1.1338x; 1.0825x over previous
//
#include <hip/hip_runtime.h>

#define HD 128   // hidden / feature dim
#define PS 32    // pooling chunks per graph

typedef __bf16 bf16x8 __attribute__((ext_vector_type(8)));
typedef float  f32x16 __attribute__((ext_vector_type(16)));
typedef unsigned short u16x4 __attribute__((ext_vector_type(4)));
typedef _Float16 f16x4 __attribute__((ext_vector_type(4)));

__device__ inline unsigned short f2bf_rne(float f) {
  unsigned u = __builtin_bit_cast(unsigned, f);
  unsigned r = u + 0x7fffu + ((u >> 16) & 1u);
  return (unsigned short)(r >> 16);
}
__device__ inline float bf2f(unsigned short h) {
  unsigned u = ((unsigned)h) << 16;
  return __builtin_bit_cast(float, u);
}
__device__ inline void cvt4(float4 f, u16x4& h, u16x4& l) {
  h[0] = f2bf_rne(f.x); l[0] = f2bf_rne(f.x - bf2f(h[0]));
  h[1] = f2bf_rne(f.y); l[1] = f2bf_rne(f.y - bf2f(h[1]));
  h[2] = f2bf_rne(f.z); l[2] = f2bf_rne(f.z - bf2f(h[2]));
  h[3] = f2bf_rne(f.w); l[3] = f2bf_rne(f.w - bf2f(h[3]));
}

// ---------------- fused prep: xsplit | wsplit | init-cnt + graph sentinels ----------------
__global__ __launch_bounds__(256) void k_prep(const float* __restrict__ x, unsigned short* __restrict__ ph,
                                              unsigned short* __restrict__ pl, int nelem4,
                                              const float* __restrict__ W1, const float* __restrict__ W2,
                                              const float* __restrict__ W3, unsigned short* __restrict__ wimg,
                                              int* __restrict__ cnt, int n, int nbX,
                                              int* __restrict__ gstart, int* __restrict__ gend, int g) {
  int b = blockIdx.x;
  int t = threadIdx.x;
  if (b < nbX) {                       // x -> split-bf16 planes (unscaled)
    int i = b * 256 + t;
    if (i < nelem4) {
      float4 f = ((const float4*)x)[i];
      u16x4 h, l;
      cvt4(f, h, l);
      ((u16x4*)ph)[i] = h;
      ((u16x4*)pl)[i] = l;
    }
  } else if (b < nbX + 51) {           // W split/transpose/pad LDS image
    int wb = b - nbX;
    const float* W = (wb < 17) ? W1 : (wb < 34) ? W2 : W3;
    unsigned short* out = wimg + (size_t)(wb / 17) * 34816;
    int base = ((wb % 17) * 256 + t) * 4;
#pragma unroll
    for (int p = 0; p < 4; ++p) {
      int flat = base + p;             // 0..17407
      int c = flat / 136, j = flat - c * 136;
      float v = (j < 128) ? W[(size_t)j * HD + c] : 0.f;
      unsigned short hi = f2bf_rne(v);
      float lo = (j < 128) ? (v - bf2f(hi)) : 0.f;
      out[(size_t)c * 136 + j] = hi;
      out[17408 + (size_t)c * 136 + j] = f2bf_rne(lo);
    }
  } else {                             // zero in-degree counters (+ sentinels, first block)
    int bb = b - nbX - 51;
    int i = bb * 256 + t;
    if (i < n) cnt[i] = 0;
    if (bb == 0 && t < g) { gstart[t] = 0x7fffffff; gend[t] = -1; }
  }
}

// ---------------- per-block exclusive scan; bsum[b] = block b's total ----------------
__global__ __launch_bounds__(256) void k_scan1(const int* __restrict__ cnt, int* __restrict__ excl,
                                               int* __restrict__ bsum, int n) {
  __shared__ int s[256];
  int tid = threadIdx.x;
  int i = blockIdx.x * 256 + tid;
  int v = (i < n) ? cnt[i] : 0;
  s[tid] = v; __syncthreads();
  for (int off = 1; off < 256; off <<= 1) {
    int t = (tid >= off) ? s[tid - off] : 0;
    __syncthreads();
    s[tid] += t;
    __syncthreads();
  }
  if (i < n) excl[i] = s[tid] - v;
  if (tid == 255) bsum[blockIdx.x] = s[255];
}

// rowptr += prefix(bsum[0..b)); dis = rsqrt(1+deg); graph ranges via sorted-batch
// boundaries. Each block computes its own bsum prefix (<=256 ints, wave 0).
__global__ __launch_bounds__(256) void k_finalize(int* __restrict__ rowptr, const int* __restrict__ bsum,
                                                  const int* __restrict__ cnt, float* __restrict__ dis,
                                                  const int* __restrict__ batch, int* __restrict__ gstart,
                                                  int* __restrict__ gend, int n) {
  __shared__ int spre;
  int tid = threadIdx.x;
  int nb = blockIdx.x;                 // need sum of bsum[0..nb)
  if (tid < 64) {
    int acc = 0;
    for (int j = tid; j < nb; j += 64) acc += bsum[j];
#pragma unroll
    for (int m = 1; m < 64; m <<= 1) acc += __shfl_xor(acc, m);
    if (tid == 0) spre = acc;
  }
  __syncthreads();
  int pre = spre;
  int i = nb * 256 + tid;
  if (i >= n) return;
  rowptr[i] += pre;
  dis[i] = rsqrtf(1.0f + (float)cnt[i]);
  int b = batch[i];
  if (i == 0 || batch[i - 1] != b) gstart[b] = i;
  if (i == n - 1 || batch[i + 1] != b) gend[b] = i;
}

// ---------------- CSR fill (atomic-free) ----------------
__global__ __launch_bounds__(256) void k_fill(const int* __restrict__ src, const int* __restrict__ dst,
                                              const int* __restrict__ rowptr, const int* __restrict__ eslot,
                                              int* __restrict__ csr, int e) {
  int i = blockIdx.x * 256 + threadIdx.x;
  if (i >= e) return;
  csr[rowptr[dst[i]] + eslot[i]] = src[i];
}

// ---------------- split-bf16 MFMA GEMM, single K=128 tile, one barrier, 16 waves ----------
// A pre-split (hi/lo ushort planes, row-scale pre-folded by producer); C = A@W in fp16
// (NO rowscale read -> no dependency on finalize). Optional tail (layer 1): in-degree
// histogram with per-edge slot record — atomic wall overlaps the GEMM's staging/MFMA.
__global__ __launch_bounds__(1024) void k_gemm(const unsigned short* __restrict__ AH,
                                               const unsigned short* __restrict__ AL,
                                               const unsigned short* __restrict__ wimg_l,
                                               _Float16* __restrict__ C, int M,
                                               const int* __restrict__ hdst, int* __restrict__ hcnt,
                                               int* __restrict__ heslot, int hE) {
  __shared__ unsigned short alds[2][128][136];   // 69632 B
  __shared__ unsigned short wlds[2][128][136];   // 69632 B
  int t = threadIdx.x;
  int row0 = blockIdx.x * 128;
  char* ab = (char*)alds;
  char* wb = (char*)wlds;
  const int PL = 128 * 272;

  // stage A: 2 planes x 2048 float4 slots (coalesced), dest padded rows
  {
    const float4* sH = (const float4*)(AH + (size_t)row0 * HD);
    const float4* sL = (const float4*)(AL + (size_t)row0 * HD);
#pragma unroll
    for (int u = 0; u < 2; ++u) {
      int s = u * 1024 + t;              // 0..2047
      int r = s >> 4, c = s & 15;
      *(float4*)(ab + r * 272 + c * 16) = sH[s];
      *(float4*)(ab + PL + r * 272 + c * 16) = sL[s];
    }
  }
  // stage W: linear copy of pre-formatted image (4352 float4)
  {
    const float4* sW = (const float4*)wimg_l;
    float4* dW = (float4*)wb;
#pragma unroll
    for (int u = 0; u < 4; ++u) dW[u * 1024 + t] = sW[u * 1024 + t];
    if (t < 256) dW[4096 + t] = sW[4096 + t];
  }
  __syncthreads();

  int w = t >> 6, lane = t & 63;
  int l31 = lane & 31, lhi = lane >> 5;
  int wr = (w >> 2) * 32, wc = (w & 3) * 32;

  f32x16 acc;
#pragma unroll
  for (int i = 0; i < 16; ++i) acc[i] = 0.f;

#pragma unroll
  for (int ks = 0; ks < 8; ++ks) {
    int ko = ks * 32 + lhi * 16;
    bf16x8 ah = *(const bf16x8*)(ab + (wr + l31) * 272 + ko);
    bf16x8 al = *(const bf16x8*)(ab + PL + (wr + l31) * 272 + ko);
    bf16x8 bh = *(const bf16x8*)(wb + (wc + l31) * 272 + ko);
    bf16x8 bl = *(const bf16x8*)(wb + PL + (wc + l31) * 272 + ko);
    acc = __builtin_amdgcn_mfma_f32_32x32x16_bf16(ah, bh, acc, 0, 0, 0);
    acc = __builtin_amdgcn_mfma_f32_32x32x16_bf16(ah, bl, acc, 0, 0, 0);
    acc = __builtin_amdgcn_mfma_f32_32x32x16_bf16(al, bh, acc, 0, 0, 0);
  }

  // epilogue: C/D layout col = lane&31, row = (r&3) + 8*(r>>2) + 4*lhi; fp16 store
  int col = wc + l31;
  int rbase = row0 + wr + 4 * lhi;
#pragma unroll
  for (int r = 0; r < 16; ++r) {
    int row = rbase + (r & 3) + 8 * (r >> 2);
    if (row < M) C[(size_t)row * HD + col] = (_Float16)acc[r];
  }

  // tail: histogram chunk (no LDS, no barrier — waves proceed independently)
  if (hdst) {
    int stride = gridDim.x * 1024;
    for (int i = blockIdx.x * 1024 + t; i < hE; i += stride)
      heslot[i] = atomicAdd(&hcnt[hdst[i]], 1);
  }
}

// ---------------- gather aggregation + self loop + bias + relu ----------------
// One HALF-WAVE per node, 4 independent row streams (r13 form — measured optimum).
// L1 variant: C rows are UNSCALED (gemm1 ran before dis existed) -> apply dis[src]
// per edge (broadcast scalar, L2-resident) and dn on the self term.
// Layers writing planes (outH path) fold dn into the output: planes hold dis[r]*h[r],
// so subsequent gemms need no rowscale (row-scaling commutes with A@W).
template <bool L1>
__global__ __launch_bounds__(256) void k_gather(const _Float16* __restrict__ C, const float* __restrict__ dis,
                                                const int* __restrict__ rowptr, const int* __restrict__ cnt,
                                                const int* __restrict__ csr, const float* __restrict__ bias,
                                                float* __restrict__ outF, unsigned short* __restrict__ outH,
                                                unsigned short* __restrict__ outL, int n) {
  int lane = threadIdx.x & 63;
  int wid = threadIdx.x >> 6;
  int half = lane >> 5;
  int l32 = lane & 31;
  int node = blockIdx.x * 8 + wid * 2 + half;
  if (node >= n) return;
  int coff = l32 * 4;
  int s = rowptr[node];
  int deg = cnt[node];

  float dn = dis[node];
  f16x4 sh = *(const f16x4*)(C + (size_t)node * HD + coff);
  float4 bb = *(const float4*)(bias + coff);

  float4 a0 = make_float4(0.f, 0.f, 0.f, 0.f);
  float4 a1 = a0, a2 = a0, a3 = a0;
  int i = 0;
  for (; i + 4 <= deg; i += 4) {          // 4 independent row streams per half-wave
    int i0 = csr[s + i];
    int i1 = csr[s + i + 1];
    int i2 = csr[s + i + 2];
    int i3 = csr[s + i + 3];
    f16x4 v0 = *(const f16x4*)(C + (size_t)i0 * HD + coff);
    f16x4 v1 = *(const f16x4*)(C + (size_t)i1 * HD + coff);
    f16x4 v2 = *(const f16x4*)(C + (size_t)i2 * HD + coff);
    f16x4 v3 = *(const f16x4*)(C + (size_t)i3 * HD + coff);
    float w0 = 1.f, w1 = 1.f, w2 = 1.f, w3 = 1.f;
    if (L1) { w0 = dis[i0]; w1 = dis[i1]; w2 = dis[i2]; w3 = dis[i3]; }
    a0.x += w0 * (float)v0[0]; a0.y += w0 * (float)v0[1]; a0.z += w0 * (float)v0[2]; a0.w += w0 * (float)v0[3];
    a1.x += w1 * (float)v1[0]; a1.y += w1 * (float)v1[1]; a1.z += w1 * (float)v1[2]; a1.w += w1 * (float)v1[3];
    a2.x += w2 * (float)v2[0]; a2.y += w2 * (float)v2[1]; a2.z += w2 * (float)v2[2]; a2.w += w2 * (float)v2[3];
    a3.x += w3 * (float)v3[0]; a3.y += w3 * (float)v3[1]; a3.z += w3 * (float)v3[2]; a3.w += w3 * (float)v3[3];
  }
  for (; i < deg; ++i) {                  // tail (up to 3)
    int i0 = csr[s + i];
    f16x4 v0 = *(const f16x4*)(C + (size_t)i0 * HD + coff);
    float w0 = L1 ? dis[i0] : 1.f;
    a0.x += w0 * (float)v0[0]; a0.y += w0 * (float)v0[1]; a0.z += w0 * (float)v0[2]; a0.w += w0 * (float)v0[3];
  }
  a0.x += a1.x + a2.x + a3.x;
  a0.y += a1.y + a2.y + a3.y;
  a0.z += a1.z + a2.z + a3.z;
  a0.w += a1.w + a2.w + a3.w;

  float ss = L1 ? dn : 1.f;               // self term: dn*C1u[node] (L1) vs prescaled C[node]
  float4 r;
  r.x = fmaxf(dn * (a0.x + ss * (float)sh[0]) + bb.x, 0.f);
  r.y = fmaxf(dn * (a0.y + ss * (float)sh[1]) + bb.y, 0.f);
  r.z = fmaxf(dn * (a0.z + ss * (float)sh[2]) + bb.z, 0.f);
  r.w = fmaxf(dn * (a0.w + ss * (float)sh[3]) + bb.w, 0.f);
  if (outF) {
    *(float4*)(outF + (size_t)node * HD + coff) = r;   // last layer: unscaled h3
  } else {
    // planes feed the next gemm: store dis[node]*h[node] (rowscale pre-folded)
    float4 rs = make_float4(dn * r.x, dn * r.y, dn * r.z, dn * r.w);
    u16x4 h, l;
    cvt4(rs, h, l);
    *(u16x4*)(outH + (size_t)node * HD + coff) = h;
    *(u16x4*)(outL + (size_t)node * HD + coff) = l;
  }
}

// ---------------- pooling stage 1 ----------------
__global__ __launch_bounds__(128) void k_pool1(const float* __restrict__ h, const int* __restrict__ gstart,
                                               const int* __restrict__ gend, float* __restrict__ psum,
                                               float* __restrict__ pmax) {
  int g = blockIdx.x, sidx = blockIdx.y, c = threadIdx.x;
  int s = gstart[g], e = gend[g];
  float sum = 0.f, mx = 0.f;
  if (s <= e) {
    int len = e - s + 1;
    int c0 = s + (int)(((long long)len * sidx) / PS);
    int c1 = s + (int)(((long long)len * (sidx + 1)) / PS);
    for (int i = c0; i < c1; ++i) {
      float v = h[(size_t)i * HD + c];
      sum += v;
      mx = fmaxf(mx, v);
    }
  }
  size_t o = ((size_t)g * PS + sidx) * HD + c;
  psum[o] = sum;
  pmax[o] = mx;
}

// ---------------- pooling stage 2 fused with MLP ----------------
__global__ __launch_bounds__(128) void k_pool2mlp(const float* __restrict__ psum, const float* __restrict__ pmax,
                                                  const int* __restrict__ gstart, const int* __restrict__ gend,
                                                  const float* __restrict__ Wf1, const float* __restrict__ bf1,
                                                  const float* __restrict__ Wf2, const float* __restrict__ bf2,
                                                  float* __restrict__ out) {
  __shared__ float p[256];
  __shared__ float red[128];
  int g = blockIdx.x, t = threadIdx.x;
  float sum = 0.f, mx = 0.f;
  for (int sidx = 0; sidx < PS; ++sidx) {
    size_t o = ((size_t)g * PS + sidx) * HD + t;
    sum += psum[o];
    mx = fmaxf(mx, pmax[o]);
  }
  int s = gstart[g], e = gend[g];
  float cntf = (s <= e) ? (float)(e - s + 1) : 1.0f;
  p[t] = sum / cntf;
  p[t + 128] = mx;
  __syncthreads();
  float acc = bf1[t];
  for (int k = 0; k < 256; ++k) acc += p[k] * Wf1[k * HD + t];
  float hv = fmaxf(acc, 0.f);
  red[t] = hv * Wf2[t];
  __syncthreads();
  for (int off = 64; off > 0; off >>= 1) {
    if (t < off) red[t] += red[t + off];
    __syncthreads();
  }
  if (t == 0) out[g] = red[0] + bf2[0];
}

extern "C" void kernel_launch(void* const* d_in, const int* in_sizes, int n_in,
                              void* d_out, int out_size, void* d_ws, size_t ws_size,
                              hipStream_t stream) {
  const float* x   = (const float*)d_in[0];
  const int*   ei  = (const int*)d_in[1];
  const int*   bat = (const int*)d_in[2];
  const float* W1  = (const float*)d_in[3];
  const float* b1  = (const float*)d_in[4];
  const float* W2  = (const float*)d_in[5];
  const float* b2  = (const float*)d_in[6];
  const float* W3  = (const float*)d_in[7];
  const float* b3  = (const float*)d_in[8];
  const float* Wf1 = (const float*)d_in[9];
  const float* bf1 = (const float*)d_in[10];
  const float* Wf2 = (const float*)d_in[11];
  const float* bf2 = (const float*)d_in[12];

  int N = in_sizes[0] / HD;
  int E = in_sizes[1] / 2;
  int G = out_size;

  int gb = (N + 127) / 128;      // gemm blocks
  int Rpad = gb * 128;           // padded row count

  char* w = (char*)d_ws;
  size_t off = 0;
  auto alloc = [&](size_t bytes) -> void* {
    void* p = w + off;
    off = (off + bytes + 255) & ~(size_t)255;
    return p;
  };
  unsigned short* pH0 = (unsigned short*)alloc((size_t)Rpad * HD * 2);
  unsigned short* pL0 = (unsigned short*)alloc((size_t)Rpad * HD * 2);
  unsigned short* pH1 = (unsigned short*)alloc((size_t)Rpad * HD * 2);
  unsigned short* pL1 = (unsigned short*)alloc((size_t)Rpad * HD * 2);
  _Float16* Cbuf = (_Float16*)alloc((size_t)Rpad * HD * 2);
  float* Hf     = (float*)alloc((size_t)N * HD * 4);
  int*   csr    = (int*)alloc((size_t)E * 4);
  int*   cnt    = (int*)alloc((size_t)N * 4);
  int*   rowptr = (int*)alloc((size_t)N * 4);
  float* dis    = (float*)alloc((size_t)N * 4);
  int*   bsum   = (int*)alloc(256 * 4);
  int*   gstart = (int*)alloc((size_t)G * 4);
  int*   gend   = (int*)alloc((size_t)G * 4);
  float* psum   = (float*)alloc((size_t)G * PS * HD * 4);
  float* pmax   = (float*)alloc((size_t)G * PS * HD * 4);
  unsigned short* wimg = (unsigned short*)alloc((size_t)3 * 34816 * 2);
  int*   eslot  = (int*)Hf;      // alias: eslot dead (after k_fill) before gather3 writes Hf

  int nbN = (N + 255) / 256;
  int nbE = (E + 255) / 256;
  int nelem4 = N * HD / 4;
  int nbX = (nelem4 + 255) / 256;

  k_prep<<<nbX + 51 + nbN, 256, 0, stream>>>(x, pH0, pL0, nelem4, W1, W2, W3, wimg, cnt, N, nbX,
                                             gstart, gend, G);
  // gemm layer 1 (UNSCALED C — no dis dependency) + histogram tail (overlapped)
  k_gemm<<<gb, 1024, 0, stream>>>(pH0, pL0, wimg, Cbuf, N, ei + E, cnt, eslot, E);
  k_scan1<<<nbN, 256, 0, stream>>>(cnt, rowptr, bsum, N);
  k_finalize<<<nbN, 256, 0, stream>>>(rowptr, bsum, cnt, dis, bat, gstart, gend, N);
  k_fill<<<nbE, 256, 0, stream>>>(ei, ei + E, rowptr, eslot, csr, E);

  int ab = (N + 7) / 8;
  k_gather<true><<<ab, 256, 0, stream>>>(Cbuf, dis, rowptr, cnt, csr, b1, nullptr, pH1, pL1, N);
  k_gemm<<<gb, 1024, 0, stream>>>(pH1, pL1, wimg + 34816, Cbuf, N, nullptr, nullptr, nullptr, 0);
  k_gather<false><<<ab, 256, 0, stream>>>(Cbuf, dis, rowptr, cnt, csr, b2, nullptr, pH0, pL0, N);
  k_gemm<<<gb, 1024, 0, stream>>>(pH0, pL0, wimg + 69632, Cbuf, N, nullptr, nullptr, nullptr, 0);
  k_gather<false><<<ab, 256, 0, stream>>>(Cbuf, dis, rowptr, cnt, csr, b3, Hf, nullptr, nullptr, N);

  dim3 pgrid(G, PS);
  k_pool1<<<pgrid, 128, 0, stream>>>(Hf, gstart, gend, psum, pmax);
  k_pool2mlp<<<G, 128, 0, stream>>>(psum, pmax, gstart, gend, Wf1, bf1, Wf2, bf2, (float*)d_out);
}